// Round 16
// baseline (280.280 us; speedup 1.0000x reference)
//
#include <hip/hip_runtime.h>

typedef __attribute__((ext_vector_type(8))) short s16x8;
typedef __attribute__((ext_vector_type(4))) float f32x4;

static __device__ __forceinline__ unsigned short f2bf(float f) {
  union { float f; unsigned int u; } v; v.f = f;
  unsigned int u = v.u;
  u += 0x7fffu + ((u >> 16) & 1u);
  return (unsigned short)(u >> 16);
}
static __device__ __forceinline__ void gload16(const void* g, void* l) {
  __builtin_amdgcn_global_load_lds((const __attribute__((address_space(1))) unsigned int*)g,
                                   (__attribute__((address_space(3))) unsigned int*)l, 16, 0, 0);
}

// ---------------------------------------------------------------- casts (fp32 -> bf16), 8 elem/thread
__global__ __launch_bounds__(256) void cast7_bf16(
    const float* __restrict__ i0, const float* __restrict__ i1, const float* __restrict__ i2,
    const float* __restrict__ i3, const float* __restrict__ i4, const float* __restrict__ i5,
    const float* __restrict__ i6,
    unsigned short* __restrict__ o0, unsigned short* __restrict__ o1,
    unsigned short* __restrict__ o2, unsigned short* __restrict__ o3,
    unsigned short* __restrict__ o4, unsigned short* __restrict__ o5,
    unsigned short* __restrict__ o6) {
  const int z = blockIdx.z;
  const float* in = z == 0 ? i0 : z == 1 ? i1 : z == 2 ? i2 : z == 3 ? i3 : z == 4 ? i4
                    : z == 5 ? i5 : i6;
  unsigned short* out = z == 0 ? o0 : z == 1 ? o1 : z == 2 ? o2 : z == 3 ? o3 : z == 4 ? o4
                        : z == 5 ? o5 : o6;
  const int n = (z < 3) ? 4194304 : 1048576;
  int i = (blockIdx.x * 256 + threadIdx.x) * 8;
  if (i >= n) return;
  float4 a = *reinterpret_cast<const float4*>(in + i);
  float4 b = *reinterpret_cast<const float4*>(in + i + 4);
  s16x8 o;
  o[0] = (short)f2bf(a.x); o[1] = (short)f2bf(a.y);
  o[2] = (short)f2bf(a.z); o[3] = (short)f2bf(a.w);
  o[4] = (short)f2bf(b.x); o[5] = (short)f2bf(b.y);
  o[6] = (short)f2bf(b.z); o[7] = (short)f2bf(b.w);
  *reinterpret_cast<s16x8*>(out + i) = o;
}

// ---------------------------------------------------------------- GEMM C = A @ W^T (bf16, K=1024)
// tile 128x128, BK=64, 4 waves (2x2), wave = 64x64 via acc[4][4].
// LDS rows are 128B, XOR-swizzled (byte ^= (row&7)<<4), pre-swizzled global src.
// z<2 blocks additionally zero-fill a balanced chunk of att's upper triangle
// in their epilogue (coalesced, after all barriers) — uses this compute-bound
// kernel's idle write BW instead of the write-saturated attn kernel's.
__global__ __launch_bounds__(256) void gemm_bf16(
    const unsigned short* __restrict__ A0, const unsigned short* __restrict__ A1,
    const unsigned short* __restrict__ A2,
    const unsigned short* __restrict__ W0, const unsigned short* __restrict__ W1,
    const unsigned short* __restrict__ W2,
    unsigned short* __restrict__ Oq, unsigned short* __restrict__ Ok,
    float* __restrict__ Kf, unsigned short* __restrict__ OvT,
    float* __restrict__ Vf, float* __restrict__ Att) {
  __shared__ __align__(16) char LDS[32768];  // As 16K | Bs 16K ; epilogue reuses all 32K

  const int z = blockIdx.z;
  const unsigned short* A = z == 0 ? A0 : z == 1 ? A1 : A2;
  const unsigned short* W = z == 0 ? W0 : z == 1 ? W1 : W2;

  const int tid = threadIdx.x, lane = tid & 63, w = tid >> 6;
  const int wm = w >> 1, wn = w & 1;
  const int row0 = blockIdx.y * 128, col0 = blockIdx.x * 128;

  f32x4 acc[4][4];
#pragma unroll
  for (int m = 0; m < 4; ++m)
#pragma unroll
    for (int n = 0; n < 4; ++n) acc[m][n] = f32x4{0.f, 0.f, 0.f, 0.f};

  const int srow = tid >> 3;
  const int swb = ((tid & 7) * 16) ^ ((srow & 7) << 4);  // pre-swizzled col byte
  const unsigned short* aSrc = A + (size_t)(row0 + srow) * 1024 + (swb >> 1);
  const unsigned short* bSrc = W + (size_t)(col0 + srow) * 1024 + (swb >> 1);
  char* ldsA = LDS + w * 1024;
  char* ldsB = LDS + 16384 + w * 1024;

  const int lr = lane & 15, g16 = (lane >> 4) * 16;

  for (int k0 = 0; k0 < 1024; k0 += 64) {
    __syncthreads();
#pragma unroll
    for (int p = 0; p < 4; ++p) gload16(aSrc + (size_t)p * 32 * 1024 + k0, ldsA + p * 4096);
#pragma unroll
    for (int p = 0; p < 4; ++p) gload16(bSrc + (size_t)p * 32 * 1024 + k0, ldsB + p * 4096);
    __syncthreads();

    s16x8 af[2][4], bf[2][4];
#pragma unroll
    for (int ks = 0; ks < 2; ++ks) {
#pragma unroll
      for (int m = 0; m < 4; ++m) {
        int r = wm * 64 + m * 16 + lr;
        int cb = (ks * 64 + g16) ^ ((r & 7) << 4);
        af[ks][m] = *reinterpret_cast<const s16x8*>(LDS + r * 128 + cb);
      }
#pragma unroll
      for (int n = 0; n < 4; ++n) {
        int r = wn * 64 + n * 16 + lr;
        int cb = (ks * 64 + g16) ^ ((r & 7) << 4);
        bf[ks][n] = *reinterpret_cast<const s16x8*>(LDS + 16384 + r * 128 + cb);
      }
    }
#pragma unroll
    for (int ks = 0; ks < 2; ++ks)
#pragma unroll
      for (int m = 0; m < 4; ++m)
#pragma unroll
        for (int n = 0; n < 4; ++n)
          acc[m][n] = __builtin_amdgcn_mfma_f32_16x16x32_bf16(af[ks][m], bf[ks][n], acc[m][n], 0, 0, 0);
  }

  const int er = (lane >> 4) * 4, ec = lane & 15;
  const int b = row0 >> 11, trow = row0 & 2047;

  {  // fp32 k/v outputs (b,h,t,64), straight from regs
    float* F = (z == 1) ? Kf : (z == 2) ? Vf : nullptr;
    if (F) {
#pragma unroll
      for (int m = 0; m < 4; ++m)
#pragma unroll
        for (int n = 0; n < 4; ++n)
#pragma unroll
          for (int j = 0; j < 4; ++j) {
            int t = trow + wm * 64 + m * 16 + er + j;
            int gd = col0 + wn * 64 + n * 16 + ec;
            F[((size_t)(b * 16 + (gd >> 6)) * 2048 + t) * 64 + (gd & 63)] = acc[m][n][j];
          }
    }
  }

  __syncthreads();
  if (z == 2) {  // V transposed bf16 (b,h,d,t) via LDS transpose staging
#pragma unroll
    for (int m = 0; m < 4; ++m)
#pragma unroll
      for (int n = 0; n < 4; ++n)
#pragma unroll
        for (int j = 0; j < 4; ++j) {
          int d = wn * 64 + n * 16 + ec, t = wm * 64 + m * 16 + er + j;
          *reinterpret_cast<short*>(LDS + d * 256 + t * 2) = (short)f2bf(acc[m][n][j]);
        }
    __syncthreads();
    const int dr = tid >> 1, half = tid & 1;
    const int gd = col0 + dr, h = gd >> 6, dd = gd & 63;
    unsigned short* dst = OvT + ((size_t)(b * 16 + h) * 64 + dd) * 2048 + trow + half * 64;
    const char* src = LDS + dr * 256 + half * 128;
#pragma unroll
    for (int i = 0; i < 8; ++i)
      *reinterpret_cast<s16x8*>(dst + i * 8) = *reinterpret_cast<const s16x8*>(src + i * 16);
  } else {  // bf16 (b,h,t,64) via LDS staging
    unsigned short* On = (z == 0) ? Oq : Ok;
#pragma unroll
    for (int m = 0; m < 4; ++m)
#pragma unroll
      for (int n = 0; n < 4; ++n)
#pragma unroll
        for (int j = 0; j < 4; ++j) {
          int r = wm * 64 + m * 16 + er + j, c = wn * 64 + n * 16 + ec;
          *reinterpret_cast<short*>(LDS + r * 256 + c * 2) = (short)f2bf(acc[m][n][j]);
        }
    __syncthreads();
    const int r = tid >> 1, half = tid & 1;
    const int h = (col0 >> 6) + half;
    unsigned short* dst = On + ((size_t)(b * 16 + h) * 2048 + trow + r) * 64;
    const char* src = LDS + r * 256 + half * 128;
#pragma unroll
    for (int i = 0; i < 8; ++i)
      *reinterpret_cast<s16x8*>(dst + i * 8) = *reinterpret_cast<const s16x8*>(src + i * 16);

    // ---- donated att zero-fill (z<2 only): chunk = (bh, slot).
    // slot<15: iblk pair (slot, 30-slot) -> constant 32x64 cols x 64 rows;
    // slot==15: single iblk 15. Coalesced float4 rows, after all barriers.
    const int lb = z * 256 + blockIdx.y * 8 + blockIdx.x;  // [0,512)
    const int zbh = lb >> 4, slot = lb & 15;
    const float4 z4 = make_float4(0.f, 0.f, 0.f, 0.f);
    const int nib = (slot == 15) ? 1 : 2;
#pragma unroll
    for (int q = 0; q < 2; ++q) {
      if (q >= nib) break;
      int ib = (q == 0) ? slot : 30 - slot;
      int c0 = (ib + 1) * 64;
      int nv = (2048 - c0) >> 2;
      for (int rr = 0; rr < 64; rr += 4) {
        int rw = rr + w;
        float4* dst4 = reinterpret_cast<float4*>(Att + ((size_t)zbh * 2048 + ib * 64 + rw) * 2048 + c0);
        for (int i = lane; i < nv; i += 64) dst4[i] = z4;
      }
    }
  }
}

// ---------------------------------------------------------------- projection GEMM, BM=64 x BN=128
// grid (8,64) = 512 blocks = 2 blocks/CU. 4 waves in N (wave = 64x32, acc[4][2]).
__global__ __launch_bounds__(256) void gemm_proj64(
    const unsigned short* __restrict__ A, const unsigned short* __restrict__ W,
    float* __restrict__ Orm) {
  __shared__ __align__(16) char LDS[24576];  // A 8K | B 16K

  const int tid = threadIdx.x, lane = tid & 63, w = tid >> 6;
  const int row0 = blockIdx.y * 64, col0 = blockIdx.x * 128;

  f32x4 acc[4][2];
#pragma unroll
  for (int m = 0; m < 4; ++m)
#pragma unroll
    for (int n = 0; n < 2; ++n) acc[m][n] = f32x4{0.f, 0.f, 0.f, 0.f};

  const int srow = tid >> 3;
  const int swb = ((tid & 7) * 16) ^ ((srow & 7) << 4);
  const unsigned short* aSrc = A + (size_t)(row0 + srow) * 1024 + (swb >> 1);
  const unsigned short* bSrc = W + (size_t)(col0 + srow) * 1024 + (swb >> 1);
  char* ldsA = LDS + w * 1024;
  char* ldsB = LDS + 8192 + w * 1024;

  const int lr = lane & 15, g16 = (lane >> 4) * 16;

  for (int k0 = 0; k0 < 1024; k0 += 64) {
    __syncthreads();
#pragma unroll
    for (int p = 0; p < 2; ++p) gload16(aSrc + (size_t)p * 32 * 1024 + k0, ldsA + p * 4096);
#pragma unroll
    for (int p = 0; p < 4; ++p) gload16(bSrc + (size_t)p * 32 * 1024 + k0, ldsB + p * 4096);
    __syncthreads();

    s16x8 af[2][4], bf[2][2];
#pragma unroll
    for (int ks = 0; ks < 2; ++ks) {
#pragma unroll
      for (int m = 0; m < 4; ++m) {
        int r = m * 16 + lr;
        int cb = (ks * 64 + g16) ^ ((r & 7) << 4);
        af[ks][m] = *reinterpret_cast<const s16x8*>(LDS + r * 128 + cb);
      }
#pragma unroll
      for (int n = 0; n < 2; ++n) {
        int r = w * 32 + n * 16 + lr;
        int cb = (ks * 64 + g16) ^ ((r & 7) << 4);
        bf[ks][n] = *reinterpret_cast<const s16x8*>(LDS + 8192 + r * 128 + cb);
      }
    }
#pragma unroll
    for (int ks = 0; ks < 2; ++ks)
#pragma unroll
      for (int m = 0; m < 4; ++m)
#pragma unroll
        for (int n = 0; n < 2; ++n)
          acc[m][n] = __builtin_amdgcn_mfma_f32_16x16x32_bf16(af[ks][m], bf[ks][n], acc[m][n], 0, 0, 0);
  }

  const int er = (lane >> 4) * 4, ec = lane & 15;
#pragma unroll
  for (int m = 0; m < 4; ++m)
#pragma unroll
    for (int n = 0; n < 2; ++n)
#pragma unroll
      for (int j = 0; j < 4; ++j)
        Orm[(size_t)(row0 + m * 16 + er + j) * 1024 + col0 + w * 32 + n * 16 + ec] = acc[m][n][j];
}

// ---------------------------------------------------------------- fused causal attention
// R12 structure minus the zero-fill tail (donated to the QKV GEMM epilogue).
#define ALD 68

__global__ __launch_bounds__(256) void attn_kernel(
    const unsigned short* __restrict__ qw, const unsigned short* __restrict__ kw,
    const unsigned short* __restrict__ vt, float* __restrict__ att_out,
    unsigned short* __restrict__ yb) {
  __shared__ __align__(16) char LDSA[2][16384];  // pass A: 128 K rows/buf; pass B: K 8K | V 8K
  __shared__ short Pl[4][16 * ALD];

  const int tid = threadIdx.x, lane = tid & 63, w = tid >> 6;
  const int flat = blockIdx.y * 32 + blockIdx.x;
  const int xcd = flat & 7, idx = flat >> 3;
  const int bh = xcd * 4 + (idx >> 5);
  const int iblk = 31 - (idx & 31);  // heavy blocks first
  const float scale2 = 0.03125f * 1.44269504f;  // 1/sqrt(1024) * log2(e)

  const int lr = lane & 15, g16 = (lane >> 4) * 16;
  const int lk = (lane >> 4) * 8, er = (lane >> 4) * 4;
  const int rbase = iblk * 64 + w * 16 + er;

  s16x8 aq[2];
  {
    const unsigned short* qb = qw + ((size_t)bh * 2048 + iblk * 64 + w * 16 + lr) * 64;
    aq[0] = *reinterpret_cast<const s16x8*>(qb + lk);
    aq[1] = *reinterpret_cast<const s16x8*>(qb + 32 + lk);
  }

  // per-lane pre-swizzled staging sources (row key = lane>>3, col byte = (lane&7)*16)
  const int sw = ((lane & 7) * 16) ^ ((lane >> 3) << 4);
  const unsigned short* kLane = kw + (size_t)bh * 131072 + (size_t)(lane >> 3) * 64 + (sw >> 1);
  const unsigned short* vLane = vt + (size_t)bh * 131072 + (size_t)(lane >> 3) * 2048 + (sw >> 1);

  float lrow[4] = {0.f, 0.f, 0.f, 0.f};

  // ---- pass A: row sums (m=0), 128 K rows per barrier, double-buffered
  {
    const int npairs = (iblk + 2) >> 1;
#pragma unroll
    for (int i = 0; i < 4; ++i)
      gload16(kLane + (size_t)(w * 32 + i * 8) * 64, LDSA[0] + w * 4096 + i * 1024);
    __syncthreads();
    int buf = 0;
    for (int p = 0; p < npairs; ++p) {
      if (p + 1 < npairs) {
#pragma unroll
        for (int i = 0; i < 4; ++i)
          gload16(kLane + (size_t)((p + 1) * 128 + w * 32 + i * 8) * 64,
                  LDSA[buf ^ 1] + w * 4096 + i * 1024);
      }
#pragma unroll
      for (int sub = 0; sub < 2; ++sub) {
        int jt = 2 * p + sub;
        if (jt > iblk) break;
        const char* Kb = LDSA[buf] + sub * 8192;
        f32x4 s[4];
#pragma unroll
        for (int n = 0; n < 4; ++n) {
          s[n] = f32x4{0.f, 0.f, 0.f, 0.f};
          int r = n * 16 + lr;
#pragma unroll
          for (int ks = 0; ks < 2; ++ks) {
            int cb = (ks * 64 + g16) ^ ((r & 7) << 4);
            s16x8 bK = *reinterpret_cast<const s16x8*>(Kb + r * 128 + cb);
            s[n] = __builtin_amdgcn_mfma_f32_16x16x32_bf16(aq[ks], bK, s[n], 0, 0, 0);
          }
        }
#pragma unroll
        for (int n = 0; n < 4; ++n) {
          int c = jt * 64 + n * 16 + lr;
#pragma unroll
          for (int j = 0; j < 4; ++j) {
            float sv = (c > rbase + j) ? -1e30f : s[n][j] * scale2;
            s[n][j] = __builtin_exp2f(sv);
          }
        }
#pragma unroll
        for (int j = 0; j < 4; ++j)
          lrow[j] += (s[0][j] + s[1][j]) + (s[2][j] + s[3][j]);
      }
      __syncthreads();
      buf ^= 1;
    }
  }

  // merge row sums across the 16 lanes of each row group
  float rl[4];
#pragma unroll
  for (int j = 0; j < 4; ++j) {
#pragma unroll
    for (int msk = 1; msk < 16; msk <<= 1) lrow[j] += __shfl_xor(lrow[j], msk);
    rl[j] = 1.0f / lrow[j];
  }

  f32x4 yacc[4];
#pragma unroll
  for (int n = 0; n < 4; ++n) yacc[n] = f32x4{0.f, 0.f, 0.f, 0.f};

  // ---- pass B: write att + PV, 64-row tiles, double-buffered, counted-vmcnt barrier
  {
    gload16(kLane + (size_t)(w * 8) * 64, LDSA[0] + w * 1024);
    gload16(kLane + (size_t)(w * 8 + 32) * 64, LDSA[0] + w * 1024 + 4096);
    gload16(vLane + (size_t)(w * 8) * 2048, LDSA[0] + 8192 + w * 1024);
    gload16(vLane + (size_t)(w * 8 + 32) * 2048, LDSA[0] + 8192 + w * 1024 + 4096);
    __syncthreads();
    int buf = 0;
    for (int jt = 0; jt <= iblk; ++jt) {
      if (jt < iblk) {
        gload16(kLane + (size_t)((jt + 1) * 64 + w * 8) * 64, LDSA[buf ^ 1] + w * 1024);
        gload16(kLane + (size_t)((jt + 1) * 64 + w * 8 + 32) * 64, LDSA[buf ^ 1] + w * 1024 + 4096);
        gload16(vLane + (size_t)(w * 8) * 2048 + (jt + 1) * 64, LDSA[buf ^ 1] + 8192 + w * 1024);
        gload16(vLane + (size_t)(w * 8 + 32) * 2048 + (jt + 1) * 64,
                LDSA[buf ^ 1] + 8192 + w * 1024 + 4096);
      }
      f32x4 s[4];
#pragma unroll
      for (int n = 0; n < 4; ++n) {
        s[n] = f32x4{0.f, 0.f, 0.f, 0.f};
        int r = n * 16 + lr;
#pragma unroll
        for (int ks = 0; ks < 2; ++ks) {
          int cb = (ks * 64 + g16) ^ ((r & 7) << 4);
          s16x8 bK = *reinterpret_cast<const s16x8*>(LDSA[buf] + r * 128 + cb);
          s[n] = __builtin_amdgcn_mfma_f32_16x16x32_bf16(aq[ks], bK, s[n], 0, 0, 0);
        }
      }
#pragma unroll
      for (int n = 0; n < 4; ++n) {
        int c = jt * 64 + n * 16 + lr;
#pragma unroll
        for (int j = 0; j < 4; ++j) {
          float sv = (c > rbase + j) ? -1e30f : s[n][j] * scale2;
          float p = __builtin_exp2f(sv) * rl[j];
          att_out[((size_t)bh * 2048 + rbase + j) * 2048 + c] = p;
          Pl[w][(er + j) * ALD + n * 16 + lr] = (short)f2bf(p);
        }
      }
#pragma unroll
      for (int ks = 0; ks < 2; ++ks) {
        s16x8 ap = *reinterpret_cast<const s16x8*>(&Pl[w][lr * ALD + ks * 32 + lk]);
#pragma unroll
        for (int n = 0; n < 4; ++n) {
          int r = n * 16 + lr;
          int cb = (ks * 64 + g16) ^ ((r & 7) << 4);
          s16x8 bv = *reinterpret_cast<const s16x8*>(LDSA[buf] + 8192 + r * 128 + cb);
          yacc[n] = __builtin_amdgcn_mfma_f32_16x16x32_bf16(ap, bv, yacc[n], 0, 0, 0);
        }
      }
      asm volatile("s_waitcnt vmcnt(16)" ::: "memory");
      __builtin_amdgcn_s_barrier();
      __builtin_amdgcn_sched_barrier(0);
      buf ^= 1;
    }
  }

  // y -> bf16 (b,t,1024), vectorized via wave-private Pl (16 shorts/lane)
  const int b = bh >> 4, h = bh & 15;
#pragma unroll
  for (int n = 0; n < 4; ++n)
#pragma unroll
    for (int j = 0; j < 4; ++j)
      Pl[w][(er + j) * ALD + n * 16 + lr] = (short)f2bf(yacc[n][j]);
  {
    const int yr = lane >> 2, ch = lane & 3;
    s16x8 v0 = *reinterpret_cast<const s16x8*>(&Pl[w][yr * ALD + ch * 16]);
    s16x8 v1 = *reinterpret_cast<const s16x8*>(&Pl[w][yr * ALD + ch * 16 + 8]);
    unsigned short* dst = yb + ((size_t)b * 2048 + iblk * 64 + w * 16 + yr) * 1024 + h * 64 + ch * 16;
    *reinterpret_cast<s16x8*>(dst) = v0;
    *reinterpret_cast<s16x8*>(dst + 8) = v1;
  }
}

// ---------------------------------------------------------------- launch
extern "C" void kernel_launch(void* const* d_in, const int* in_sizes, int n_in,
                              void* d_out, int out_size, void* d_ws, size_t ws_size,
                              hipStream_t stream) {
  (void)in_sizes; (void)n_in; (void)out_size; (void)ws_size;
  const float* Q = (const float*)d_in[0];
  const float* K = (const float*)d_in[1];
  const float* V = (const float*)d_in[2];
  const float* Wq = (const float*)d_in[3];
  const float* Wk = (const float*)d_in[4];
  const float* Wv = (const float*)d_in[5];
  const float* Wp = (const float*)d_in[6];
  float* out = (float*)d_out;

  char* ws = (char*)d_ws;
  const size_t MB = 1024 * 1024;
  unsigned short* qb = (unsigned short*)(ws + 0 * MB);
  unsigned short* kb = (unsigned short*)(ws + 8 * MB);
  unsigned short* vb = (unsigned short*)(ws + 16 * MB);
  unsigned short* wqb = (unsigned short*)(ws + 24 * MB);
  unsigned short* wkb = (unsigned short*)(ws + 26 * MB);
  unsigned short* wvb = (unsigned short*)(ws + 28 * MB);
  unsigned short* wpb = (unsigned short*)(ws + 30 * MB);
  unsigned short* qws = (unsigned short*)(ws + 32 * MB);
  unsigned short* kws = (unsigned short*)(ws + 40 * MB);
  unsigned short* vwt = (unsigned short*)(ws + 48 * MB);
  unsigned short* yb = (unsigned short*)(ws + 0 * MB);  // reuses qb (dead after QKV GEMM)

  float* att_out = out + 4194304;
  float* k_out = out + 138412032;
  float* v_out = out + 142606336;

  cast7_bf16<<<dim3(2048, 1, 7), 256, 0, stream>>>(Q, K, V, Wq, Wk, Wv, Wp,
                                                   qb, kb, vb, wqb, wkb, wvb, wpb);

  gemm_bf16<<<dim3(8, 32, 3), 256, 0, stream>>>(qb, kb, vb, wqb, wkb, wvb,
                                                qws, kws, k_out, vwt, v_out, att_out);

  attn_kernel<<<dim3(32, 32), 256, 0, stream>>>(qws, kws, vwt, att_out, yb);

  gemm_proj64<<<dim3(8, 64), 256, 0, stream>>>(yb, wpb, out);
}

// Round 17
// 246.125 us; speedup vs baseline: 1.1388x; 1.1388x over previous
//
#include <hip/hip_runtime.h>

typedef __attribute__((ext_vector_type(8))) short s16x8;
typedef __attribute__((ext_vector_type(4))) float f32x4;

static __device__ __forceinline__ unsigned short f2bf(float f) {
  union { float f; unsigned int u; } v; v.f = f;
  unsigned int u = v.u;
  u += 0x7fffu + ((u >> 16) & 1u);
  return (unsigned short)(u >> 16);
}
static __device__ __forceinline__ void gload16(const void* g, void* l) {
  __builtin_amdgcn_global_load_lds((const __attribute__((address_space(1))) unsigned int*)g,
                                   (__attribute__((address_space(3))) unsigned int*)l, 16, 0, 0);
}

// ---------------------------------------------------------------- casts (fp32 -> bf16), 8 elem/thread
__global__ __launch_bounds__(256) void cast7_bf16(
    const float* __restrict__ i0, const float* __restrict__ i1, const float* __restrict__ i2,
    const float* __restrict__ i3, const float* __restrict__ i4, const float* __restrict__ i5,
    const float* __restrict__ i6,
    unsigned short* __restrict__ o0, unsigned short* __restrict__ o1,
    unsigned short* __restrict__ o2, unsigned short* __restrict__ o3,
    unsigned short* __restrict__ o4, unsigned short* __restrict__ o5,
    unsigned short* __restrict__ o6) {
  const int z = blockIdx.z;
  const float* in = z == 0 ? i0 : z == 1 ? i1 : z == 2 ? i2 : z == 3 ? i3 : z == 4 ? i4
                    : z == 5 ? i5 : i6;
  unsigned short* out = z == 0 ? o0 : z == 1 ? o1 : z == 2 ? o2 : z == 3 ? o3 : z == 4 ? o4
                        : z == 5 ? o5 : o6;
  const int n = (z < 3) ? 4194304 : 1048576;
  int i = (blockIdx.x * 256 + threadIdx.x) * 8;
  if (i >= n) return;
  float4 a = *reinterpret_cast<const float4*>(in + i);
  float4 b = *reinterpret_cast<const float4*>(in + i + 4);
  s16x8 o;
  o[0] = (short)f2bf(a.x); o[1] = (short)f2bf(a.y);
  o[2] = (short)f2bf(a.z); o[3] = (short)f2bf(a.w);
  o[4] = (short)f2bf(b.x); o[5] = (short)f2bf(b.y);
  o[6] = (short)f2bf(b.z); o[7] = (short)f2bf(b.w);
  *reinterpret_cast<s16x8*>(out + i) = o;
}

// ---------------------------------------------------------------- GEMM C = A @ W^T (bf16, K=1024)
// tile 128x128, BK=64, 4 waves (2x2), wave = 64x64 via acc[4][4].
// LDS rows are 128B, XOR-swizzled (byte ^= (row&7)<<4), pre-swizzled global src.
__global__ __launch_bounds__(256) void gemm_bf16(
    const unsigned short* __restrict__ A0, const unsigned short* __restrict__ A1,
    const unsigned short* __restrict__ A2,
    const unsigned short* __restrict__ W0, const unsigned short* __restrict__ W1,
    const unsigned short* __restrict__ W2,
    unsigned short* __restrict__ Oq, unsigned short* __restrict__ Ok,
    float* __restrict__ Kf, unsigned short* __restrict__ OvT,
    float* __restrict__ Vf) {
  __shared__ __align__(16) char LDS[32768];  // As 16K | Bs 16K ; epilogue reuses all 32K

  const int z = blockIdx.z;
  const unsigned short* A = z == 0 ? A0 : z == 1 ? A1 : A2;
  const unsigned short* W = z == 0 ? W0 : z == 1 ? W1 : W2;

  const int tid = threadIdx.x, lane = tid & 63, w = tid >> 6;
  const int wm = w >> 1, wn = w & 1;
  const int row0 = blockIdx.y * 128, col0 = blockIdx.x * 128;

  f32x4 acc[4][4];
#pragma unroll
  for (int m = 0; m < 4; ++m)
#pragma unroll
    for (int n = 0; n < 4; ++n) acc[m][n] = f32x4{0.f, 0.f, 0.f, 0.f};

  const int srow = tid >> 3;
  const int swb = ((tid & 7) * 16) ^ ((srow & 7) << 4);  // pre-swizzled col byte
  const unsigned short* aSrc = A + (size_t)(row0 + srow) * 1024 + (swb >> 1);
  const unsigned short* bSrc = W + (size_t)(col0 + srow) * 1024 + (swb >> 1);
  char* ldsA = LDS + w * 1024;
  char* ldsB = LDS + 16384 + w * 1024;

  const int lr = lane & 15, g16 = (lane >> 4) * 16;

  for (int k0 = 0; k0 < 1024; k0 += 64) {
    __syncthreads();
#pragma unroll
    for (int p = 0; p < 4; ++p) gload16(aSrc + (size_t)p * 32 * 1024 + k0, ldsA + p * 4096);
#pragma unroll
    for (int p = 0; p < 4; ++p) gload16(bSrc + (size_t)p * 32 * 1024 + k0, ldsB + p * 4096);
    __syncthreads();

    s16x8 af[2][4], bf[2][4];
#pragma unroll
    for (int ks = 0; ks < 2; ++ks) {
#pragma unroll
      for (int m = 0; m < 4; ++m) {
        int r = wm * 64 + m * 16 + lr;
        int cb = (ks * 64 + g16) ^ ((r & 7) << 4);
        af[ks][m] = *reinterpret_cast<const s16x8*>(LDS + r * 128 + cb);
      }
#pragma unroll
      for (int n = 0; n < 4; ++n) {
        int r = wn * 64 + n * 16 + lr;
        int cb = (ks * 64 + g16) ^ ((r & 7) << 4);
        bf[ks][n] = *reinterpret_cast<const s16x8*>(LDS + 16384 + r * 128 + cb);
      }
    }
#pragma unroll
    for (int ks = 0; ks < 2; ++ks)
#pragma unroll
      for (int m = 0; m < 4; ++m)
#pragma unroll
        for (int n = 0; n < 4; ++n)
          acc[m][n] = __builtin_amdgcn_mfma_f32_16x16x32_bf16(af[ks][m], bf[ks][n], acc[m][n], 0, 0, 0);
  }

  const int er = (lane >> 4) * 4, ec = lane & 15;
  const int b = row0 >> 11, trow = row0 & 2047;

  {  // fp32 k/v outputs (b,h,t,64), straight from regs
    float* F = (z == 1) ? Kf : (z == 2) ? Vf : nullptr;
    if (F) {
#pragma unroll
      for (int m = 0; m < 4; ++m)
#pragma unroll
        for (int n = 0; n < 4; ++n)
#pragma unroll
          for (int j = 0; j < 4; ++j) {
            int t = trow + wm * 64 + m * 16 + er + j;
            int gd = col0 + wn * 64 + n * 16 + ec;
            F[((size_t)(b * 16 + (gd >> 6)) * 2048 + t) * 64 + (gd & 63)] = acc[m][n][j];
          }
    }
  }

  __syncthreads();
  if (z == 2) {  // V transposed bf16 (b,h,d,t) via LDS transpose staging
#pragma unroll
    for (int m = 0; m < 4; ++m)
#pragma unroll
      for (int n = 0; n < 4; ++n)
#pragma unroll
        for (int j = 0; j < 4; ++j) {
          int d = wn * 64 + n * 16 + ec, t = wm * 64 + m * 16 + er + j;
          *reinterpret_cast<short*>(LDS + d * 256 + t * 2) = (short)f2bf(acc[m][n][j]);
        }
    __syncthreads();
    const int dr = tid >> 1, half = tid & 1;
    const int gd = col0 + dr, h = gd >> 6, dd = gd & 63;
    unsigned short* dst = OvT + ((size_t)(b * 16 + h) * 64 + dd) * 2048 + trow + half * 64;
    const char* src = LDS + dr * 256 + half * 128;
#pragma unroll
    for (int i = 0; i < 8; ++i)
      *reinterpret_cast<s16x8*>(dst + i * 8) = *reinterpret_cast<const s16x8*>(src + i * 16);
  } else {  // bf16 (b,h,t,64) via LDS staging
    unsigned short* On = (z == 0) ? Oq : Ok;
#pragma unroll
    for (int m = 0; m < 4; ++m)
#pragma unroll
      for (int n = 0; n < 4; ++n)
#pragma unroll
        for (int j = 0; j < 4; ++j) {
          int r = wm * 64 + m * 16 + er + j, c = wn * 64 + n * 16 + ec;
          *reinterpret_cast<short*>(LDS + r * 256 + c * 2) = (short)f2bf(acc[m][n][j]);
        }
    __syncthreads();
    const int r = tid >> 1, half = tid & 1;
    const int h = (col0 >> 6) + half;
    unsigned short* dst = On + ((size_t)(b * 16 + h) * 2048 + trow + r) * 64;
    const char* src = LDS + r * 256 + half * 128;
#pragma unroll
    for (int i = 0; i < 8; ++i)
      *reinterpret_cast<s16x8*>(dst + i * 8) = *reinterpret_cast<const s16x8*>(src + i * 16);
  }
}

// ---------------------------------------------------------------- projection GEMM, BM=64 x BN=128
// grid (8,64) = 512 blocks = 2 blocks/CU. 4 waves in N (wave = 64x32, acc[4][2]).
__global__ __launch_bounds__(256) void gemm_proj64(
    const unsigned short* __restrict__ A, const unsigned short* __restrict__ W,
    float* __restrict__ Orm) {
  __shared__ __align__(16) char LDS[24576];  // A 8K | B 16K

  const int tid = threadIdx.x, lane = tid & 63, w = tid >> 6;
  const int row0 = blockIdx.y * 64, col0 = blockIdx.x * 128;

  f32x4 acc[4][2];
#pragma unroll
  for (int m = 0; m < 4; ++m)
#pragma unroll
    for (int n = 0; n < 2; ++n) acc[m][n] = f32x4{0.f, 0.f, 0.f, 0.f};

  const int srow = tid >> 3;
  const int swb = ((tid & 7) * 16) ^ ((srow & 7) << 4);
  const unsigned short* aSrc = A + (size_t)(row0 + srow) * 1024 + (swb >> 1);
  const unsigned short* bSrc = W + (size_t)(col0 + srow) * 1024 + (swb >> 1);
  char* ldsA = LDS + w * 1024;
  char* ldsB = LDS + 8192 + w * 1024;

  const int lr = lane & 15, g16 = (lane >> 4) * 16;

  for (int k0 = 0; k0 < 1024; k0 += 64) {
    __syncthreads();
#pragma unroll
    for (int p = 0; p < 2; ++p) gload16(aSrc + (size_t)p * 32 * 1024 + k0, ldsA + p * 4096);
#pragma unroll
    for (int p = 0; p < 4; ++p) gload16(bSrc + (size_t)p * 32 * 1024 + k0, ldsB + p * 4096);
    __syncthreads();

    s16x8 af[2][4], bf[2][2];
#pragma unroll
    for (int ks = 0; ks < 2; ++ks) {
#pragma unroll
      for (int m = 0; m < 4; ++m) {
        int r = m * 16 + lr;
        int cb = (ks * 64 + g16) ^ ((r & 7) << 4);
        af[ks][m] = *reinterpret_cast<const s16x8*>(LDS + r * 128 + cb);
      }
#pragma unroll
      for (int n = 0; n < 2; ++n) {
        int r = w * 32 + n * 16 + lr;
        int cb = (ks * 64 + g16) ^ ((r & 7) << 4);
        bf[ks][n] = *reinterpret_cast<const s16x8*>(LDS + 8192 + r * 128 + cb);
      }
    }
#pragma unroll
    for (int ks = 0; ks < 2; ++ks)
#pragma unroll
      for (int m = 0; m < 4; ++m)
#pragma unroll
        for (int n = 0; n < 2; ++n)
          acc[m][n] = __builtin_amdgcn_mfma_f32_16x16x32_bf16(af[ks][m], bf[ks][n], acc[m][n], 0, 0, 0);
  }

  const int er = (lane >> 4) * 4, ec = lane & 15;
#pragma unroll
  for (int m = 0; m < 4; ++m)
#pragma unroll
    for (int n = 0; n < 2; ++n)
#pragma unroll
      for (int j = 0; j < 4; ++j)
        Orm[(size_t)(row0 + m * 16 + er + j) * 1024 + col0 + w * 32 + n * 16 + ec] = acc[m][n][j];
}

// ---------------------------------------------------------------- fused causal attention
// R6/R11 structure; pass-B per-tile barrier uses counted s_waitcnt vmcnt(16) +
// raw s_barrier (T4) so att stores drain in the background.
#define ALD 68

__global__ __launch_bounds__(256) void attn_kernel(
    const unsigned short* __restrict__ qw, const unsigned short* __restrict__ kw,
    const unsigned short* __restrict__ vt, float* __restrict__ att_out,
    unsigned short* __restrict__ yb) {
  __shared__ __align__(16) char LDSA[2][16384];  // pass A: 128 K rows/buf; pass B: K 8K | V 8K
  __shared__ short Pl[4][16 * ALD];

  const int tid = threadIdx.x, lane = tid & 63, w = tid >> 6;
  const int flat = blockIdx.y * 32 + blockIdx.x;
  const int xcd = flat & 7, idx = flat >> 3;
  const int bh = xcd * 4 + (idx >> 5);
  const int iblk = 31 - (idx & 31);  // heavy blocks first
  const float scale2 = 0.03125f * 1.44269504f;  // 1/sqrt(1024) * log2(e)

  const int lr = lane & 15, g16 = (lane >> 4) * 16;
  const int lk = (lane >> 4) * 8, er = (lane >> 4) * 4;
  const int rbase = iblk * 64 + w * 16 + er;

  s16x8 aq[2];
  {
    const unsigned short* qb = qw + ((size_t)bh * 2048 + iblk * 64 + w * 16 + lr) * 64;
    aq[0] = *reinterpret_cast<const s16x8*>(qb + lk);
    aq[1] = *reinterpret_cast<const s16x8*>(qb + 32 + lk);
  }

  // per-lane pre-swizzled staging sources (row key = lane>>3, col byte = (lane&7)*16)
  const int sw = ((lane & 7) * 16) ^ ((lane >> 3) << 4);
  const unsigned short* kLane = kw + (size_t)bh * 131072 + (size_t)(lane >> 3) * 64 + (sw >> 1);
  const unsigned short* vLane = vt + (size_t)bh * 131072 + (size_t)(lane >> 3) * 2048 + (sw >> 1);

  float lrow[4] = {0.f, 0.f, 0.f, 0.f};

  // ---- pass A: row sums (m=0), 128 K rows per barrier, double-buffered
  {
    const int npairs = (iblk + 2) >> 1;
#pragma unroll
    for (int i = 0; i < 4; ++i)
      gload16(kLane + (size_t)(w * 32 + i * 8) * 64, LDSA[0] + w * 4096 + i * 1024);
    __syncthreads();
    int buf = 0;
    for (int p = 0; p < npairs; ++p) {
      if (p + 1 < npairs) {
#pragma unroll
        for (int i = 0; i < 4; ++i)
          gload16(kLane + (size_t)((p + 1) * 128 + w * 32 + i * 8) * 64,
                  LDSA[buf ^ 1] + w * 4096 + i * 1024);
      }
#pragma unroll
      for (int sub = 0; sub < 2; ++sub) {
        int jt = 2 * p + sub;
        if (jt > iblk) break;
        const char* Kb = LDSA[buf] + sub * 8192;
        f32x4 s[4];
#pragma unroll
        for (int n = 0; n < 4; ++n) {
          s[n] = f32x4{0.f, 0.f, 0.f, 0.f};
          int r = n * 16 + lr;
#pragma unroll
          for (int ks = 0; ks < 2; ++ks) {
            int cb = (ks * 64 + g16) ^ ((r & 7) << 4);
            s16x8 bK = *reinterpret_cast<const s16x8*>(Kb + r * 128 + cb);
            s[n] = __builtin_amdgcn_mfma_f32_16x16x32_bf16(aq[ks], bK, s[n], 0, 0, 0);
          }
        }
#pragma unroll
        for (int n = 0; n < 4; ++n) {
          int c = jt * 64 + n * 16 + lr;
#pragma unroll
          for (int j = 0; j < 4; ++j) {
            float sv = (c > rbase + j) ? -1e30f : s[n][j] * scale2;
            s[n][j] = __builtin_exp2f(sv);
          }
        }
#pragma unroll
        for (int j = 0; j < 4; ++j)
          lrow[j] += (s[0][j] + s[1][j]) + (s[2][j] + s[3][j]);
      }
      __syncthreads();
      buf ^= 1;
    }
  }

  // merge row sums across the 16 lanes of each row group
  float rl[4];
#pragma unroll
  for (int j = 0; j < 4; ++j) {
#pragma unroll
    for (int msk = 1; msk < 16; msk <<= 1) lrow[j] += __shfl_xor(lrow[j], msk);
    rl[j] = 1.0f / lrow[j];
  }

  f32x4 yacc[4];
#pragma unroll
  for (int n = 0; n < 4; ++n) yacc[n] = f32x4{0.f, 0.f, 0.f, 0.f};

  // ---- pass B: write att + PV, 64-row tiles, double-buffered, counted-vmcnt barrier
  {
    gload16(kLane + (size_t)(w * 8) * 64, LDSA[0] + w * 1024);
    gload16(kLane + (size_t)(w * 8 + 32) * 64, LDSA[0] + w * 1024 + 4096);
    gload16(vLane + (size_t)(w * 8) * 2048, LDSA[0] + 8192 + w * 1024);
    gload16(vLane + (size_t)(w * 8 + 32) * 2048, LDSA[0] + 8192 + w * 1024 + 4096);
    __syncthreads();
    int buf = 0;
    for (int jt = 0; jt <= iblk; ++jt) {
      if (jt < iblk) {
        gload16(kLane + (size_t)((jt + 1) * 64 + w * 8) * 64, LDSA[buf ^ 1] + w * 1024);
        gload16(kLane + (size_t)((jt + 1) * 64 + w * 8 + 32) * 64, LDSA[buf ^ 1] + w * 1024 + 4096);
        gload16(vLane + (size_t)(w * 8) * 2048 + (jt + 1) * 64, LDSA[buf ^ 1] + 8192 + w * 1024);
        gload16(vLane + (size_t)(w * 8 + 32) * 2048 + (jt + 1) * 64,
                LDSA[buf ^ 1] + 8192 + w * 1024 + 4096);
      }
      f32x4 s[4];
#pragma unroll
      for (int n = 0; n < 4; ++n) {
        s[n] = f32x4{0.f, 0.f, 0.f, 0.f};
        int r = n * 16 + lr;
#pragma unroll
        for (int ks = 0; ks < 2; ++ks) {
          int cb = (ks * 64 + g16) ^ ((r & 7) << 4);
          s16x8 bK = *reinterpret_cast<const s16x8*>(LDSA[buf] + r * 128 + cb);
          s[n] = __builtin_amdgcn_mfma_f32_16x16x32_bf16(aq[ks], bK, s[n], 0, 0, 0);
        }
      }
#pragma unroll
      for (int n = 0; n < 4; ++n) {
        int c = jt * 64 + n * 16 + lr;
#pragma unroll
        for (int j = 0; j < 4; ++j) {
          float sv = (c > rbase + j) ? -1e30f : s[n][j] * scale2;
          float p = __builtin_exp2f(sv) * rl[j];
          att_out[((size_t)bh * 2048 + rbase + j) * 2048 + c] = p;
          Pl[w][(er + j) * ALD + n * 16 + lr] = (short)f2bf(p);
        }
      }
#pragma unroll
      for (int ks = 0; ks < 2; ++ks) {
        s16x8 ap = *reinterpret_cast<const s16x8*>(&Pl[w][lr * ALD + ks * 32 + lk]);
#pragma unroll
        for (int n = 0; n < 4; ++n) {
          int r = n * 16 + lr;
          int cb = (ks * 64 + g16) ^ ((r & 7) << 4);
          s16x8 bv = *reinterpret_cast<const s16x8*>(LDSA[buf] + 8192 + r * 128 + cb);
          yacc[n] = __builtin_amdgcn_mfma_f32_16x16x32_bf16(ap, bv, yacc[n], 0, 0, 0);
        }
      }
      // T4: wait only until the 4 next-tile gload16 (issued before the 16 att
      // stores) have landed; the newest 16 stores keep draining across the
      // barrier instead of stalling the wave at vmcnt(0).
      asm volatile("s_waitcnt vmcnt(16)" ::: "memory");
      __builtin_amdgcn_s_barrier();
      __builtin_amdgcn_sched_barrier(0);
      buf ^= 1;
    }
  }

  // y -> bf16 (b,t,1024), vectorized via wave-private Pl (16 shorts/lane)
  const int b = bh >> 4, h = bh & 15;
#pragma unroll
  for (int n = 0; n < 4; ++n)
#pragma unroll
    for (int j = 0; j < 4; ++j)
      Pl[w][(er + j) * ALD + n * 16 + lr] = (short)f2bf(yacc[n][j]);
  {
    const int yr = lane >> 2, ch = lane & 3;
    s16x8 v0 = *reinterpret_cast<const s16x8*>(&Pl[w][yr * ALD + ch * 16]);
    s16x8 v1 = *reinterpret_cast<const s16x8*>(&Pl[w][yr * ALD + ch * 16 + 8]);
    unsigned short* dst = yb + ((size_t)b * 2048 + iblk * 64 + w * 16 + yr) * 1024 + h * 64 + ch * 16;
    *reinterpret_cast<s16x8*>(dst) = v0;
    *reinterpret_cast<s16x8*>(dst + 8) = v1;
  }

  // zero-fill above-diagonal tail
  int c0 = (iblk + 1) * 64;
  if (c0 < 2048) {
    int nv = (2048 - c0) >> 2;
    const float4 z4 = make_float4(0.f, 0.f, 0.f, 0.f);
    for (int rr = 0; rr < 64; rr += 4) {
      int r = rr + w;
      float4* dst = reinterpret_cast<float4*>(att_out + ((size_t)bh * 2048 + iblk * 64 + r) * 2048 + c0);
      for (int i = lane; i < nv; i += 64) dst[i] = z4;
    }
  }
}

// ---------------------------------------------------------------- launch
extern "C" void kernel_launch(void* const* d_in, const int* in_sizes, int n_in,
                              void* d_out, int out_size, void* d_ws, size_t ws_size,
                              hipStream_t stream) {
  (void)in_sizes; (void)n_in; (void)out_size; (void)ws_size;
  const float* Q = (const float*)d_in[0];
  const float* K = (const float*)d_in[1];
  const float* V = (const float*)d_in[2];
  const float* Wq = (const float*)d_in[3];
  const float* Wk = (const float*)d_in[4];
  const float* Wv = (const float*)d_in[5];
  const float* Wp = (const float*)d_in[6];
  float* out = (float*)d_out;

  char* ws = (char*)d_ws;
  const size_t MB = 1024 * 1024;
  unsigned short* qb = (unsigned short*)(ws + 0 * MB);
  unsigned short* kb = (unsigned short*)(ws + 8 * MB);
  unsigned short* vb = (unsigned short*)(ws + 16 * MB);
  unsigned short* wqb = (unsigned short*)(ws + 24 * MB);
  unsigned short* wkb = (unsigned short*)(ws + 26 * MB);
  unsigned short* wvb = (unsigned short*)(ws + 28 * MB);
  unsigned short* wpb = (unsigned short*)(ws + 30 * MB);
  unsigned short* qws = (unsigned short*)(ws + 32 * MB);
  unsigned short* kws = (unsigned short*)(ws + 40 * MB);
  unsigned short* vwt = (unsigned short*)(ws + 48 * MB);
  unsigned short* yb = (unsigned short*)(ws + 0 * MB);  // reuses qb (dead after QKV GEMM)

  float* att_out = out + 4194304;
  float* k_out = out + 138412032;
  float* v_out = out + 142606336;

  cast7_bf16<<<dim3(2048, 1, 7), 256, 0, stream>>>(Q, K, V, Wq, Wk, Wv, Wp,
                                                   qb, kb, vb, wqb, wkb, wvb, wpb);

  gemm_bf16<<<dim3(8, 32, 3), 256, 0, stream>>>(qb, kb, vb, wqb, wkb, wvb,
                                                qws, kws, k_out, vwt, v_out);

  attn_kernel<<<dim3(32, 32), 256, 0, stream>>>(qws, kws, vwt, att_out, yb);

  gemm_proj64<<<dim3(8, 64), 256, 0, stream>>>(yb, wpb, out);
}